// Round 1
// baseline (244.145 us; speedup 1.0000x reference)
//
#include <hip/hip_runtime.h>
#include <cstdint>

// B=4096, T=512, I=3, H=32, C=3
#define B_TOT 4096
#define T_LEN 512
#define LOG2E 1.44269504088896340736f

typedef _Float16 f16x8 __attribute__((ext_vector_type(8)));
typedef _Float16 f16x4 __attribute__((ext_vector_type(4)));
typedef _Float16 f16x2 __attribute__((ext_vector_type(2)));
typedef float    f32x4 __attribute__((ext_vector_type(4)));
typedef unsigned int u32x4 __attribute__((ext_vector_type(4)));

__device__ __forceinline__ float ex2(float v)  { return __builtin_amdgcn_exp2f(v); }
__device__ __forceinline__ float rcp_(float v) { return __builtin_amdgcn_rcpf(v); }

// R14: wave-exclusive recurrence — ZERO barriers in the 512-step loop.
// Each wave owns 4 batches (cols = batch n&3, dup x4). 8 gate-MFMAs/step
// compute all 128 gate rows with row map R(j,m)=32*(j&3)+8*(m>>2)+4*(j>>2)+(m&3),
// so lane (n,kq), d=n>>2 keeps gates of hids 8kq+2d,8kq+2d+1 at
// acc[(d>=2)?g+4:g][2*(d&1)+e]  (24 cndmask selects, masks in SGPRs).
// After gate math, (h0,h1) pack into 1 dword; 4 ds_swizzle (keep bits {0,1,4},
// force bits {2,3}=d') rebuild the next step's B-fragment h[8kq+j][b] fully
// in-register: the C/D lane layout IS the B lane layout here. h,c never touch LDS.
// x folded via a 2nd MFMA: A2e has W_ih+bias in K-slots 0-3 (even step),
// A2o in slots 4-7 (odd step) -> one ds_read_b128 of staged x feeds 2 steps
// with no per-step shuffles (unused K slots have A==0, B finite).
// 1024 single-wave blocks -> 1 wave on every SIMD of the chip.
__global__ __launch_bounds__(64, 1)
void lstm_wv(const float* __restrict__ x,
             const float* __restrict__ W_ih,
             const float* __restrict__ W_hh,
             const float* __restrict__ b_ih,
             const float* __restrict__ b_hh,
             const float* __restrict__ W_fc,
             const float* __restrict__ b_fc,
             float* __restrict__ out)
{
    __shared__ __align__(16) _Float16 xbuf[T_LEN / 2][4][8];  // 16 KB: 2 steps/row
    __shared__ float hfin[4][32];

    const int lane = threadIdx.x;
    const int n    = lane & 15;
    const int kq   = lane >> 4;    // 0..3: K-slot group / output row group
    const int b    = n & 3;        // local batch (column)
    const int d    = n >> 2;       // dup index 0..3
    const int gb0  = blockIdx.x << 2;

    // ---- weights: gate-MFMA A frags (row = n), x-MFMA A frags (even/odd) ----
    f16x8 aW[8], A2e[8], A2o[8];
#pragma unroll
    for (int j = 0; j < 8; ++j) {
        const int   g   = j & 3;
        const int   R   = 32 * g + 8 * d + 4 * (j >> 2) + b;   // R(j, n)
        const float smj = (g == 2) ? (-2.0f * LOG2E) : (-LOG2E);
#pragma unroll
        for (int jj = 0; jj < 8; ++jj)
            aW[j][jj] = (_Float16)(smj * W_hh[R * 32 + 8 * kq + jj]);
        f16x8 e = {}, o = {};
        if (kq == 0) {
            const _Float16 w0 = (_Float16)(smj * W_ih[R * 3 + 0]);
            const _Float16 w1 = (_Float16)(smj * W_ih[R * 3 + 1]);
            const _Float16 w2 = (_Float16)(smj * W_ih[R * 3 + 2]);
            const _Float16 wb = (_Float16)(smj * (b_ih[R] + b_hh[R]));
            e[0] = w0; e[1] = w1; e[2] = w2; e[3] = wb;
            o[4] = w0; o[5] = w1; o[6] = w2; o[7] = wb;
        }
        A2e[j] = e; A2o[j] = o;
    }

    // ---- stage all T steps of x as f16 {x0,x1,x2,1} step-pairs (one-time) ----
    for (int s = 0; s < 32; ++s) {
        const int id = lane + (s << 6);          // 0..2047 = 4 batches x 512 t
        const int t = id >> 2, bb = id & 3;
        const float* xg = x + ((size_t)(gb0 + bb) * T_LEN + t) * 3;
        f16x4 v;
        v[0] = (_Float16)xg[0]; v[1] = (_Float16)xg[1];
        v[2] = (_Float16)xg[2]; v[3] = (_Float16)1.0f;
        *(f16x4*)&xbuf[t >> 1][bb][(t & 1) << 2] = v;
    }
    __syncthreads();   // the ONLY pre-loop barrier (1-wave block: ~free)

    const bool selj = (d >= 2);
    const bool selr = (d & 1) != 0;
    const f32x4 z = {0.f, 0.f, 0.f, 0.f};

    u32x4 bhu = {0u, 0u, 0u, 0u};   // B-fragment of h(t), h(0)=0
    float c0 = 0.f, c1 = 0.f;
    float h0 = 0.f, h1 = 0.f;

    f16x8 xp = *(const f16x8*)&xbuf[0][b][0];

    for (int t2 = 0; t2 < T_LEN / 2; ++t2) {
        // prefetch next step-pair's x (wraps to dummy on last iter)
        const f16x8 xpN = *(const f16x8*)&xbuf[(t2 + 1) & (T_LEN / 2 - 1)][b][0];
#pragma unroll
        for (int par = 0; par < 2; ++par) {
            f32x4 acc[8];
#pragma unroll
            for (int j = 0; j < 8; ++j) {
                const f32x4 ax = __builtin_amdgcn_mfma_f32_16x16x32_f16(
                    par ? A2o[j] : A2e[j], xp, z, 0, 0, 0);
                acc[j] = __builtin_amdgcn_mfma_f32_16x16x32_f16(
                    aW[j], __builtin_bit_cast(f16x8, bhu), ax, 0, 0, 0);
            }
            // pick this lane's 2 states (gates i,f,g,o each): 24 cndmask
            float av[4][2];
#pragma unroll
            for (int g = 0; g < 4; ++g) {
                const float v0 = selj ? acc[g + 4][0] : acc[g][0];
                const float v1 = selj ? acc[g + 4][1] : acc[g][1];
                const float v2 = selj ? acc[g + 4][2] : acc[g][2];
                const float v3 = selj ? acc[g + 4][3] : acc[g][3];
                av[g][0] = selr ? v2 : v0;
                av[g][1] = selr ? v3 : v1;
            }
            // merged-reciprocal gate math (same numerics as R13)
            {
                const float ei = ex2(av[0][0]), ef = ex2(av[1][0]);
                const float eg = ex2(av[2][0]), eo = ex2(av[3][0]);
                const float pi = 1.f + ei, pf = 1.f + ef, pg = 1.f + eg;
                const float mg = 1.f - eg;
                const float pp = pi * pg, qn = mg * pf;
                c0 = fmaf(c0, pp, qn) * rcp_(pf * pp);
                const float ec = ex2(c0 * (-2.0f * LOG2E));
                const float po = 1.f + eo, pc = 1.f + ec, mc = 1.f - ec;
                h0 = mc * rcp_(po * pc);
            }
            {
                const float ei = ex2(av[0][1]), ef = ex2(av[1][1]);
                const float eg = ex2(av[2][1]), eo = ex2(av[3][1]);
                const float pi = 1.f + ei, pf = 1.f + ef, pg = 1.f + eg;
                const float mg = 1.f - eg;
                const float pp = pi * pg, qn = mg * pf;
                c1 = fmaf(c1, pp, qn) * rcp_(pf * pp);
                const float ec = ex2(c1 * (-2.0f * LOG2E));
                const float po = 1.f + eo, pc = 1.f + ec, mc = 1.f - ec;
                h1 = mc * rcp_(po * pc);
            }
            // pack (h0,h1) -> 1 dword; gather dup-quad -> next B-fragment
            f16x2 hp; hp[0] = (_Float16)h0; hp[1] = (_Float16)h1;
            const int pk = __builtin_bit_cast(int, hp);
            // src_lane = (lane & 0b10011) | (d'<<2)  : keep {b, kq-bit}, force d'
            bhu[0] = (unsigned)__builtin_amdgcn_ds_swizzle(pk, 0x0013);
            bhu[1] = (unsigned)__builtin_amdgcn_ds_swizzle(pk, 0x0093);
            bhu[2] = (unsigned)__builtin_amdgcn_ds_swizzle(pk, 0x0113);
            bhu[3] = (unsigned)__builtin_amdgcn_ds_swizzle(pk, 0x0193);
        }
        xp = xpN;
    }

    // ---- epilogue: tiny FC on final h ----
    hfin[b][8 * kq + 2 * d + 0] = h0;
    hfin[b][8 * kq + 2 * d + 1] = h1;
    __syncthreads();
    if (lane < 12) {
        const int m = lane / 3, cc = lane - 3 * m;
        float acc = b_fc[cc];
#pragma unroll
        for (int k = 0; k < 32; ++k)
            acc = fmaf(W_fc[cc * 32 + k], hfin[m][k], acc);
        out[(gb0 + m) * 3 + cc] = acc;
    }
}

extern "C" void kernel_launch(void* const* d_in, const int* in_sizes, int n_in,
                              void* d_out, int out_size, void* d_ws, size_t ws_size,
                              hipStream_t stream) {
    const float* x    = (const float*)d_in[0];
    const float* W_ih = (const float*)d_in[1];
    const float* W_hh = (const float*)d_in[2];
    const float* b_ih = (const float*)d_in[3];
    const float* b_hh = (const float*)d_in[4];
    const float* W_fc = (const float*)d_in[5];
    const float* b_fc = (const float*)d_in[6];
    float* out = (float*)d_out;

    dim3 grid(B_TOT / 4);   // 1024 single-wave workgroups -> 1 wave/SIMD chip-wide
    dim3 block(64);
    lstm_wv<<<grid, block, 0, stream>>>(x, W_ih, W_hh, b_ih, b_hh, W_fc, b_fc, out);
}